// Round 13
// baseline (374.394 us; speedup 1.0000x reference)
//
#include <hip/hip_runtime.h>
#include <hip/hip_bf16.h>

// ---------------------------------------------------------------------------
// MultiHeadAttention_21887153340754
// N=4096, IN=1000(pad 1024), H1=2048, H2=1024, EMB=512, HEADS=8, depth=64, OUT=1000
//
// Attention is LINEAR in scores (no softmax):
//   out = Σ_h (q̂_h/8/den) @ (M_h @ Wo_h) + b = q̃ @ MW + b,  M_h = k̂_h^T v_h
//
// Round 13: A-operand via registers (global->VGPR, double-buffered named
// sets), B-only in LDS (ring-3 + swizzle). Rationale: r12 decomposition
// shows the ~2660cy/K-tile wall is ~58% LDS pipe (48KB traffic/block-tile);
// A's LDS round-trip reconstructs plain per-lane loads (swizzles cancel to
// colgroup=fq), so it can be deleted: LDS traffic 48KB -> 16KB/block-tile.
// Skeleton otherwise = r12 best (vmcnt(0)+barrier per tile, 128-row tiles,
// 4 waves, 3 blocks/CU even packing, XCD rect map).
// ---------------------------------------------------------------------------

typedef __attribute__((ext_vector_type(4))) float f32x4;
typedef __attribute__((ext_vector_type(4))) float float4v;
typedef __attribute__((ext_vector_type(8))) short bf16x8;

// ---- workspace layout (bytes) ---------------------------------------------
static constexpr size_t OFF_XB   = 0;                      // bf16 [4096][1024]
static constexpr size_t OFF_WT1  = OFF_XB   + 8388608;     // bf16 [3][2048][1024]
static constexpr size_t OFF_WT2  = OFF_WT1  + 12582912;    // bf16 [3][1024][2048]
static constexpr size_t OFF_WT3  = OFF_WT2  + 12582912;    // bf16 [3][512][1024]
static constexpr size_t OFF_MWT  = OFF_WT3  + 3145728;     // bf16 [1024][512]  (MW^T)
static constexpr size_t OFF_B1C  = OFF_MWT  + 1048576;     // (unused hole)
static constexpr size_t OFF_H1   = OFF_B1C  + 24576;       // bf16 [4096][6144]
static constexpr size_t OFF_H2   = OFF_H1   + 50331648;    // bf16 [4096][3072]
static constexpr size_t OFF_QKV  = OFF_H2   + 25165824;    // bf16 [4096][1536]
static constexpr size_t OFF_MP   = OFF_QKV  + 12582912;    // f32  [32][8][4160]
static constexpr size_t OFF_MF   = OFF_MP   + 4259840;     // f32  [8][4160]
static constexpr size_t OFF_QT   = OFF_MF   + 133120;      // bf16 [4096][512]  (q̃)

__device__ __forceinline__ void gload16(const __hip_bfloat16* g, __hip_bfloat16* l) {
  __builtin_amdgcn_global_load_lds(
      (const __attribute__((address_space(1))) void*)g,
      (__attribute__((address_space(3))) void*)l, 16, 0, 0);
}

// XCD rect map with z folded into the linear dispatch id. HW linear id =
// (z*gy + y)*gx + x, XCD = id%8 (round-robin). Each XCD gets a cm x cn tile
// rectangle per z; slots walk m-first. Requires (gy/cm)*(gx/cn) == 8.
__device__ __forceinline__ void xcd_map(int gx, int gy, int cm, int cn,
                                        int& zz, int& mt, int& nt) {
  const int gid = (blockIdx.z * gy + blockIdx.y) * gx + blockIdx.x;
  const int xcd = gid & 7;
  const int slot = gid >> 3;
  const int per = cm * cn;
  zz = slot / per;
  const int rem = slot % per;
  const int nxr = gx / cn;
  const int xr = xcd % nxr, yr = xcd / nxr;
  mt = yr * cm + rem % cm;
  nt = xr * cn + rem / cm;
}

// ---- mega-prep v2: 9 weight transposes (fp32 [K][N] -> bf16 [N][Kpad]) ----
__global__ __launch_bounds__(256) void prep(
    const float* __restrict__ w1a, const float* __restrict__ w1b, const float* __restrict__ w1c,
    const float* __restrict__ w2a, const float* __restrict__ w2b, const float* __restrict__ w2c,
    const float* __restrict__ w3a, const float* __restrict__ w3b, const float* __restrict__ w3c,
    const float* __restrict__ batch,
    __hip_bfloat16* __restrict__ WT1, __hip_bfloat16* __restrict__ WT2,
    __hip_bfloat16* __restrict__ WT3, __hip_bfloat16* __restrict__ XB) {
  const int b = blockIdx.x, t = threadIdx.x;
  if (b >= 3456) {                                   // batch conv region
    int idx = (b - 3456) * 256 + t;
    int row = idx >> 8, c4 = (idx & 255) * 4;
    __hip_bfloat16 o[4];
    if (c4 < 1000) {
      float4v v = *reinterpret_cast<const float4v*>(&batch[(size_t)row * 1000 + c4]);
#pragma unroll
      for (int j = 0; j < 4; ++j) o[j] = __float2bfloat16(v[j]);
    } else {
#pragma unroll
      for (int j = 0; j < 4; ++j) o[j] = __float2bfloat16(0.f);
    }
    *reinterpret_cast<ushort4*>(&XB[(size_t)row * 1024 + c4]) =
        *reinterpret_cast<const ushort4*>(o);
    return;
  }
  __shared__ float tl[64][65];
  const float* in; __hip_bfloat16* out; int K, N, Kpad, kb, nb;
  if (b < 1536) {                                    // w1: 16 ktiles x 32 ntiles
    int mat = b / 512, r = b % 512;
    const float* s[3] = {w1a, w1b, w1c};
    in = s[mat]; out = WT1 + (size_t)mat * 2048 * 1024;
    K = 1000; N = 2048; Kpad = 1024; kb = r & 15; nb = r >> 4;
  } else if (b < 3072) {                             // w2: 32 ktiles x 16 ntiles
    int r = b - 1536; int mat = r / 512; r %= 512;
    const float* s[3] = {w2a, w2b, w2c};
    in = s[mat]; out = WT2 + (size_t)mat * 1024 * 2048;
    K = 2048; N = 1024; Kpad = 2048; kb = r & 31; nb = r >> 5;
  } else {                                           // w3: 16 ktiles x 8 ntiles
    int r = b - 3072; int mat = r / 128; r %= 128;
    const float* s[3] = {w3a, w3b, w3c};
    in = s[mat]; out = WT3 + (size_t)mat * 512 * 1024;
    K = 1024; N = 512; Kpad = 1024; kb = r & 15; nb = r >> 4;
  }
  const int kb64 = kb * 64, nb64 = nb * 64;
  const int trow = t >> 4, tc4 = (t & 15) * 4;
#pragma unroll
  for (int it = 0; it < 4; ++it) {
    const int kl = it * 16 + trow;
    const int k = kb64 + kl;
    float4v v = {0.f, 0.f, 0.f, 0.f};
    if (k < K) v = *reinterpret_cast<const float4v*>(&in[(size_t)k * N + nb64 + tc4]);
    tl[kl][tc4 + 0] = v[0]; tl[kl][tc4 + 1] = v[1];
    tl[kl][tc4 + 2] = v[2]; tl[kl][tc4 + 3] = v[3];
  }
  __syncthreads();
  const int ln = t >> 2, ks = (t & 3) * 16;
  short ob[16];
#pragma unroll
  for (int u = 0; u < 16; ++u) {
    __hip_bfloat16 bb = __float2bfloat16(tl[ks + u][ln]);
    ob[u] = *(const short*)&bb;
  }
  __hip_bfloat16* dst = out + (size_t)(nb64 + ln) * Kpad + kb64 + ks;
  *reinterpret_cast<bf16x8*>(dst) = *reinterpret_cast<const bf16x8*>(&ob[0]);
  *reinterpret_cast<bf16x8*>(dst + 8) = *reinterpret_cast<const bf16x8*>(&ob[8]);
}

// ---------------------------------------------------------------------------
// gemm_ar<NJ>: 128 x (NJ*32) tile, BK=32, 4 waves (2m x 2n). A-operand loaded
// global->VGPR (double-buffered named sets afA/afB; per-lane addresses equal
// what the old LDS round-trip produced, swizzles cancel). B staged in LDS
// ring-3 with swizzle. One vmcnt(0)+barrier per K-tile (A(T) and B(T+1) each
// get a full tile-time of flight; all NT call sites are even).
// epi: 1 = bf16+relu (bias by zz), 2 = f32 guarded col<nlimit (bias0),
//      3 = bf16 + relu iff zz<2, 4 = bf16+relu, bias col-select (G1 merged).
// ---------------------------------------------------------------------------
template <int NJ>
__global__ __launch_bounds__(256, 3) void gemm_ar(
    const __hip_bfloat16* __restrict__ A, int lda, size_t Az,
    const __hip_bfloat16* __restrict__ B, int ldb, size_t Bz,
    const float* __restrict__ bias0, const float* __restrict__ bias1,
    const float* __restrict__ bias2,
    void* __restrict__ Cout, int ldc, size_t Cz,
    int nlimit, int NT, int epi, int cm, int cn) {
  __shared__ __hip_bfloat16 smB[3][NJ * 1024];       // [buf][NJ*32 rows x 32]
  const int t = threadIdx.x;
  int zz, mt, nt;
  xcd_map(gridDim.x, gridDim.y, cm, cn, zz, mt, nt);
  const int m0 = mt * 128, n0 = nt * (NJ * 32);
  A += (size_t)zz * Az;
  B += (size_t)zz * Bz;

  const int w = t >> 6, l = t & 63;
  const int wm = (w >> 1) * 64, wn = (w & 1) * (NJ * 16);
  const int fr = l & 15, fq = l >> 4;

  // B staging (unchanged r12 pattern): thread t -> LDS byte t*16;
  // linear byte L: row=L>>6, slot=(L>>4)&3, colgroup = slot^((row>>1)&3)
  const int r0 = t >> 2;
  const int cg = (t & 3) ^ ((t >> 3) & 3);
  const __hip_bfloat16* gB0 = B + (size_t)(n0 + r0) * ldb + cg * 8;
  const __hip_bfloat16* gB1 = gB0 + (size_t)64 * ldb;   // used only if NJ==4

  // B ds_read offsets: row*32 + (fq ^ ((row>>1)&3))*8
  const int soff = (fq ^ ((fr >> 1) & 3)) * 8;
  int offB[NJ];
#pragma unroll
  for (int j = 0; j < NJ; ++j) offB[j] = (wn + j * 16 + fr) * 32 + soff;

  // A direct per-lane pointers (constant all kernel; per-tile offset folds
  // into the 13-bit load immediate: KT*64B <= 4032)
  const __hip_bfloat16* aP[4];
#pragma unroll
  for (int i = 0; i < 4; ++i)
    aP[i] = A + (size_t)(m0 + wm + i * 16 + fr) * lda + fq * 8;

  f32x4 acc[4][NJ] = {};
  bf16x8 afA[4], afB[4];

#define STGB(BUF, KT) do {                                                     \
    const size_t ko_ = (size_t)(KT) * 32;                                      \
    gload16(gB0 + ko_, &smB[BUF][w * 512]);                                    \
    if (NJ == 4) gload16(gB1 + ko_, &smB[BUF][w * 512 + 2048]);                \
  } while (0)

#define LOADA(DST, KT) do {                                                    \
    _Pragma("unroll") for (int i_ = 0; i_ < 4; ++i_)                           \
      DST[i_] = *reinterpret_cast<const bf16x8*>(aP[i_] + (size_t)(KT) * 32);  \
  } while (0)

#define MM(AF, BF) do {                                                        \
    _Pragma("unroll") for (int i_ = 0; i_ < 4; ++i_)                           \
      _Pragma("unroll") for (int j_ = 0; j_ < NJ; ++j_)                        \
        acc[i_][j_] = __builtin_amdgcn_mfma_f32_16x16x32_bf16(                 \
            AF[i_], BF[j_], acc[i_][j_], 0, 0, 0);                             \
  } while (0)

  // prologue: A(0) to regs; B tiles 0,1 to LDS bufs 0,1
  LOADA(afA, 0);
  STGB(0, 0);
  STGB(1, 1);

  int cur = 0;                                       // buf of tile TT
  for (int TT = 0; TT < NT; TT += 2) {
    const int b1 = (cur + 1 >= 3) ? cur - 2 : cur + 1;
    const int b2 = (cur + 2 >= 3) ? cur - 1 : cur + 2;
    // ---- tile TT (uses afA) ----
    asm volatile("s_waitcnt vmcnt(0)" ::: "memory"); // A(TT), B(TT) landed
    __builtin_amdgcn_s_barrier();
    __builtin_amdgcn_sched_barrier(0);
    bf16x8 bfa[NJ];
#pragma unroll
    for (int j = 0; j < NJ; ++j)
      bfa[j] = *reinterpret_cast<const bf16x8*>(&smB[cur][offB[j]]);
    if (TT + 2 < NT) STGB(b2, TT + 2);
    if (TT + 1 < NT) LOADA(afB, TT + 1);
    MM(afA, bfa);
    // ---- tile TT+1 (uses afB) ----
    if (TT + 1 < NT) {
      asm volatile("s_waitcnt vmcnt(0)" ::: "memory");
      __builtin_amdgcn_s_barrier();                  // all bfa reads done ->
      __builtin_amdgcn_sched_barrier(0);             // buf cur reusable below
      bf16x8 bfb[NJ];
#pragma unroll
      for (int j = 0; j < NJ; ++j)
        bfb[j] = *reinterpret_cast<const bf16x8*>(&smB[b1][offB[j]]);
      if (TT + 3 < NT) STGB(cur, TT + 3);
      if (TT + 2 < NT) LOADA(afA, TT + 2);
      MM(afB, bfb);
    }
    cur = (cur + 2 >= 3) ? cur - 1 : cur + 2;
  }
#undef STGB
#undef LOADA
#undef MM

  // epilogue
  const float* bz = (zz == 0) ? bias0 : ((zz == 1) ? bias1 : bias2);
  const bool dorelu = (epi == 1) || (epi == 4) || (epi == 3 && zz < 2);
  float bv[NJ];
#pragma unroll
  for (int j = 0; j < NJ; ++j) {
    const int col = n0 + wn + j * 16 + fr;
    if (epi == 4) {
      const float* bsel = (col < 2048) ? bias0 : ((col < 4096) ? bias1 : bias2);
      bv[j] = bsel[col & 2047];
    } else if (epi == 2) {
      bv[j] = (col < nlimit) ? bias0[col] : 0.f;
    } else {
      bv[j] = bz[col];
    }
  }
#pragma unroll
  for (int i = 0; i < 4; ++i) {
#pragma unroll
    for (int j = 0; j < NJ; ++j) {
      const int col = n0 + wn + j * 16 + fr;
#pragma unroll
      for (int rr = 0; rr < 4; ++rr) {
        const int row = m0 + wm + i * 16 + fq * 4 + rr;
        float v = acc[i][j][rr] + bv[j];
        if (dorelu) v = fmaxf(v, 0.f);
        if (epi == 2) {
          if (col < nlimit)
            ((float*)Cout)[(size_t)row * ldc + col] = v;
        } else {
          ((__hip_bfloat16*)Cout + (size_t)zz * Cz)[(size_t)row * ldc + col] =
              __float2bfloat16(v);
        }
      }
    }
  }
}

// ---- per-head partial M = kh^T vh (64x64) and ksum, over 128-row chunks ---
__global__ __launch_bounds__(256) void kv_outer(const __hip_bfloat16* __restrict__ QKV, int ld,
                                                float* __restrict__ part) {
  __shared__ __hip_bfloat16 kt[128][64];
  __shared__ __hip_bfloat16 vt[128][64];
  const int t = threadIdx.x;
  const int n0 = blockIdx.x * 128;
  const int h = blockIdx.y;
#pragma unroll
  for (int it = 0; it < 4; ++it) {
    int r = it * 32 + (t >> 3);
    int c = (t & 7) * 8;
    const __hip_bfloat16* kr = &QKV[(size_t)(n0 + r) * ld + 512 + h * 64 + c];
    const __hip_bfloat16* vr = &QKV[(size_t)(n0 + r) * ld + 1024 + h * 64 + c];
    *reinterpret_cast<bf16x8*>(&kt[r][c]) = *reinterpret_cast<const bf16x8*>(kr);
    *reinterpret_cast<bf16x8*>(&vt[r][c]) = *reinterpret_cast<const bf16x8*>(vr);
  }
  __syncthreads();
  const int i = t >> 2, j0 = (t & 3) << 4;
  float acc[16] = {};
  float ks = 0.f;
  for (int r = 0; r < 128; ++r) {
    float kv = __bfloat162float(kt[r][i]);
    ks += kv;
    bf16x8 va = *reinterpret_cast<const bf16x8*>(&vt[r][j0]);
    bf16x8 vb = *reinterpret_cast<const bf16x8*>(&vt[r][j0 + 8]);
#pragma unroll
    for (int jj = 0; jj < 8; ++jj) {
      ushort ua = (ushort)((const short*)&va)[jj];
      ushort ub = (ushort)((const short*)&vb)[jj];
      acc[jj]     += kv * __bfloat162float(*(const __hip_bfloat16*)&ua);
      acc[8 + jj] += kv * __bfloat162float(*(const __hip_bfloat16*)&ub);
    }
  }
  float* dst = part + ((size_t)blockIdx.x * 8 + h) * 4160;
#pragma unroll
  for (int jj = 0; jj < 16; ++jj) dst[i * 64 + j0 + jj] = acc[jj];
  if ((t & 3) == 0) dst[4096 + i] = ks;
}

// ---- reduce 32 partials -> Mfin [8][4160]; 130 blocks x 256 threads -------
__global__ __launch_bounds__(256) void reduce_m(const float* __restrict__ part,
                                                float* __restrict__ Mfin) {
  const int g = blockIdx.x * 256 + threadIdx.x;      // 33280 = 8*4160 exactly
  if (g >= 8 * 4160) return;
  const int h = g / 4160, idx = g % 4160;
  float s = 0.f;
#pragma unroll 4
  for (int c = 0; c < 32; ++c) s += part[((size_t)c * 8 + h) * 4160 + idx];
  Mfin[(size_t)h * 4160 + idx] = s;
}

// ---- fused: blocks [0,32): MW^T = M_h @ Wo_h (bf16); [32,1056): q̃ --------
__global__ __launch_bounds__(256) void mwq(const float* __restrict__ Mfin,
                                           const float* __restrict__ wo,
                                           __hip_bfloat16* __restrict__ MWT,
                                           const __hip_bfloat16* __restrict__ QKV,
                                           __hip_bfloat16* __restrict__ QT) {
  const int t = threadIdx.x;
  if (blockIdx.x < 32) {
    __shared__ float Ml[64][64];
    const int h = blockIdx.x >> 2;
    const int j = (blockIdx.x & 3) * 256 + t;
    const float* M = Mfin + (size_t)h * 4160;
    for (int e = t; e < 4096; e += 256)
      Ml[e >> 6][e & 63] = M[e];
    __syncthreads();
    float wcol[64];
    const bool valid = (j < 1000);
#pragma unroll
    for (int d = 0; d < 64; ++d)
      wcol[d] = valid ? wo[(size_t)(h * 64 + d) * 1000 + j] : 0.f;
    short ob[64];
#pragma unroll
    for (int i = 0; i < 64; ++i) {
      float a = 0.f;
#pragma unroll
      for (int d = 0; d < 64; ++d) a += Ml[i][d] * wcol[d];
      __hip_bfloat16 bb = __float2bfloat16(a);
      ob[i] = *(const short*)&bb;
    }
    __hip_bfloat16* dst = MWT + (size_t)j * 512 + h * 64;
#pragma unroll
    for (int v = 0; v < 8; ++v)
      *reinterpret_cast<bf16x8*>(dst + v * 8) = *reinterpret_cast<const bf16x8*>(&ob[v * 8]);
  } else {
    const int bid = blockIdx.x - 32;
    const int r = bid * 4 + (t >> 6);
    const int c = (t & 63) * 8;
    const int h = (t & 63) >> 3;
    bf16x8 qv = *reinterpret_cast<const bf16x8*>(&QKV[(size_t)r * 1536 + c]);
    float qf[8];
#pragma unroll
    for (int j = 0; j < 8; ++j) {
      ushort u = (ushort)((const short*)&qv)[j];
      qf[j] = __bfloat162float(*(const __hip_bfloat16*)&u);
    }
    const float* ks = Mfin + (size_t)h * 4160 + 4096 + (c & 63);
    float s = 0.f;
#pragma unroll
    for (int j = 0; j < 8; ++j) s += qf[j] * ks[j];
    s += __shfl_xor(s, 1, 8);
    s += __shfl_xor(s, 2, 8);
    s += __shfl_xor(s, 4, 8);
    const float inv = 0.125f / (s * 0.125f + 1e-8f);
    bf16x8 o;
#pragma unroll
    for (int j = 0; j < 8; ++j) {
      __hip_bfloat16 bb = __float2bfloat16(qf[j] * inv);
      ((short*)&o)[j] = *(const short*)&bb;
    }
    *reinterpret_cast<bf16x8*>(&QT[(size_t)r * 512 + c]) = o;
  }
}

// ---------------------------------------------------------------------------
extern "C" void kernel_launch(void* const* d_in, const int* in_sizes, int n_in,
                              void* d_out, int out_size, void* d_ws, size_t ws_size,
                              hipStream_t stream) {
  const float* batch = (const float*)d_in[0];
  const float* w1[3] = {(const float*)d_in[1],  (const float*)d_in[7],  (const float*)d_in[13]};
  const float* b1[3] = {(const float*)d_in[2],  (const float*)d_in[8],  (const float*)d_in[14]};
  const float* w2[3] = {(const float*)d_in[3],  (const float*)d_in[9],  (const float*)d_in[15]};
  const float* b2[3] = {(const float*)d_in[4],  (const float*)d_in[10], (const float*)d_in[16]};
  const float* w3[3] = {(const float*)d_in[5],  (const float*)d_in[11], (const float*)d_in[17]};
  const float* b3[3] = {(const float*)d_in[6],  (const float*)d_in[12], (const float*)d_in[18]};
  const float* wow   = (const float*)d_in[19];
  const float* wob   = (const float*)d_in[20];

  char* ws = (char*)d_ws;
  __hip_bfloat16* XB  = (__hip_bfloat16*)(ws + OFF_XB);
  __hip_bfloat16* WT1 = (__hip_bfloat16*)(ws + OFF_WT1);
  __hip_bfloat16* WT2 = (__hip_bfloat16*)(ws + OFF_WT2);
  __hip_bfloat16* WT3 = (__hip_bfloat16*)(ws + OFF_WT3);
  __hip_bfloat16* MWT = (__hip_bfloat16*)(ws + OFF_MWT);
  __hip_bfloat16* H1  = (__hip_bfloat16*)(ws + OFF_H1);
  __hip_bfloat16* H2  = (__hip_bfloat16*)(ws + OFF_H2);
  __hip_bfloat16* QKV = (__hip_bfloat16*)(ws + OFF_QKV);
  float*          MP  = (float*)(ws + OFF_MP);
  float*          MF  = (float*)(ws + OFF_MF);
  __hip_bfloat16* QT  = (__hip_bfloat16*)(ws + OFF_QT);
  float*          OUT = (float*)d_out;

  // 1) mega-prep: all weight transposes + batch pad/convert (1 launch)
  prep<<<7552, 256, 0, stream>>>(w1[0], w1[1], w1[2], w2[0], w2[1], w2[2],
                                 w3[0], w3[1], w3[2], batch, WT1, WT2, WT3, XB);

  // 2) MLPs (gemm_ar: A in regs, B in LDS ring-3; even 3 blocks/CU)
  // G1 (merged q|k|v): [4096,1024]@[1024,6144] -> H1. 1536 blocks = 2 even rounds.
  gemm_ar<4><<<dim3(48, 32, 1), 256, 0, stream>>>(
      XB, 1024, 0, WT1, 1024, 0, b1[0], b1[1], b1[2], H1, 6144, 0,
      6144, 32, 4, 16, 12);
  // G2 z-batched: [4096,2048]@[2048,1024] -> H2 (relu). 768 blocks = 3/CU even.
  gemm_ar<4><<<dim3(8, 32, 3), 256, 0, stream>>>(
      H1, 6144, 2048, WT2, 2048, (size_t)1024 * 2048,
      b2[0], b2[1], b2[2], H2, 3072, 1024, 1024, 64, 1, 8, 4);
  // G3 z-batched: [4096,1024]@[1024,512] -> QKV. 128x64 tiles, 768 blocks even.
  gemm_ar<2><<<dim3(8, 32, 3), 256, 0, stream>>>(
      H2, 3072, 1024, WT3, 1024, (size_t)512 * 1024,
      b3[0], b3[1], b3[2], QKV, 1536, 512, 512, 32, 3, 8, 4);

  // 3) attention reductions + fusion into out-proj operands
  kv_outer<<<dim3(32, 8), 256, 0, stream>>>(QKV, 1536, MP);
  reduce_m<<<130, 256, 0, stream>>>(MP, MF);
  mwq<<<1056, 256, 0, stream>>>(MF, wow, MWT, QKV, QT);

  // 4) fused attention+output projection: q̃ @ MW^T -> d_out fp32.
  // 128x64 tiles -> 512 blocks = 2/CU even.
  gemm_ar<2><<<dim3(16, 32, 1), 256, 0, stream>>>(
      QT, 512, 0, MWT, 512, 0, wob, wob, wob, OUT, 1000, 0,
      1000, 16, 2, 16, 4);

  (void)in_sizes; (void)n_in; (void)out_size; (void)ws_size;
}

// Round 14
// 237.901 us; speedup vs baseline: 1.5737x; 1.5737x over previous
//
#include <hip/hip_runtime.h>
#include <hip/hip_bf16.h>

// ---------------------------------------------------------------------------
// MultiHeadAttention_21887153340754
// N=4096, IN=1000(pad 1024), H1=2048, H2=1024, EMB=512, HEADS=8, depth=64, OUT=1000
//
// Attention is LINEAR in scores (no softmax):
//   out = Σ_h (q̂_h/8/den) @ (M_h @ Wo_h) + b = q̃ @ MW + b,  M_h = k̂_h^T v_h
//
// Round 14: REVERT to round-12 (best measured: 238.0 µs). Round-13's
// A-in-registers cut LDS traffic but replaced dense 1KB global_load_lds
// staging with 16-row x 64B per-wave scatter loads -> VMEM efficiency
// collapse (123 µs/GEMM). Round-12 config restored byte-identical:
//  - gemm_fast<NJ>: 128-row tiles, BK=32, 4 waves, ring-3 LDS + counted
//    vmcnt, swizzled global_load_lds staging, even 3-blocks/CU packing.
//  - mega-prep, fused attention (kv_outer/reduce_m/mwq), XCD rect map.
// Structural floor of this decomposition: ~890 cy/CU/K-tile =
// ~380 LDS-read + ~130 LDS-write + ~310 MFMA/issue (LDS-pipe dominated).
// ---------------------------------------------------------------------------

typedef __attribute__((ext_vector_type(4))) float f32x4;
typedef __attribute__((ext_vector_type(4))) float float4v;
typedef __attribute__((ext_vector_type(8))) short bf16x8;

// ---- workspace layout (bytes) ---------------------------------------------
static constexpr size_t OFF_XB   = 0;                      // bf16 [4096][1024]
static constexpr size_t OFF_WT1  = OFF_XB   + 8388608;     // bf16 [3][2048][1024]
static constexpr size_t OFF_WT2  = OFF_WT1  + 12582912;    // bf16 [3][1024][2048]
static constexpr size_t OFF_WT3  = OFF_WT2  + 12582912;    // bf16 [3][512][1024]
static constexpr size_t OFF_MWT  = OFF_WT3  + 3145728;     // bf16 [1024][512]  (MW^T)
static constexpr size_t OFF_B1C  = OFF_MWT  + 1048576;     // (unused hole)
static constexpr size_t OFF_H1   = OFF_B1C  + 24576;       // bf16 [4096][6144]
static constexpr size_t OFF_H2   = OFF_H1   + 50331648;    // bf16 [4096][3072]
static constexpr size_t OFF_QKV  = OFF_H2   + 25165824;    // bf16 [4096][1536]
static constexpr size_t OFF_MP   = OFF_QKV  + 12582912;    // f32  [32][8][4160]
static constexpr size_t OFF_MF   = OFF_MP   + 4259840;     // f32  [8][4160]
static constexpr size_t OFF_QT   = OFF_MF   + 133120;      // bf16 [4096][512]  (q̃)

__device__ __forceinline__ void gload16(const __hip_bfloat16* g, __hip_bfloat16* l) {
  __builtin_amdgcn_global_load_lds(
      (const __attribute__((address_space(1))) void*)g,
      (__attribute__((address_space(3))) void*)l, 16, 0, 0);
}

// XCD rect map with z folded into the linear dispatch id. HW linear id =
// (z*gy + y)*gx + x, XCD = id%8 (round-robin). Each XCD gets a cm x cn tile
// rectangle per z; slots walk m-first. Requires (gy/cm)*(gx/cn) == 8.
__device__ __forceinline__ void xcd_map(int gx, int gy, int cm, int cn,
                                        int& zz, int& mt, int& nt) {
  const int gid = (blockIdx.z * gy + blockIdx.y) * gx + blockIdx.x;
  const int xcd = gid & 7;
  const int slot = gid >> 3;
  const int per = cm * cn;
  zz = slot / per;
  const int rem = slot % per;
  const int nxr = gx / cn;
  const int xr = xcd % nxr, yr = xcd / nxr;
  mt = yr * cm + rem % cm;
  nt = xr * cn + rem / cm;
}

// ---- mega-prep v2: 9 weight transposes (fp32 [K][N] -> bf16 [N][Kpad]) ----
__global__ __launch_bounds__(256) void prep(
    const float* __restrict__ w1a, const float* __restrict__ w1b, const float* __restrict__ w1c,
    const float* __restrict__ w2a, const float* __restrict__ w2b, const float* __restrict__ w2c,
    const float* __restrict__ w3a, const float* __restrict__ w3b, const float* __restrict__ w3c,
    const float* __restrict__ batch,
    __hip_bfloat16* __restrict__ WT1, __hip_bfloat16* __restrict__ WT2,
    __hip_bfloat16* __restrict__ WT3, __hip_bfloat16* __restrict__ XB) {
  const int b = blockIdx.x, t = threadIdx.x;
  if (b >= 3456) {                                   // batch conv region
    int idx = (b - 3456) * 256 + t;
    int row = idx >> 8, c4 = (idx & 255) * 4;
    __hip_bfloat16 o[4];
    if (c4 < 1000) {
      float4v v = *reinterpret_cast<const float4v*>(&batch[(size_t)row * 1000 + c4]);
#pragma unroll
      for (int j = 0; j < 4; ++j) o[j] = __float2bfloat16(v[j]);
    } else {
#pragma unroll
      for (int j = 0; j < 4; ++j) o[j] = __float2bfloat16(0.f);
    }
    *reinterpret_cast<ushort4*>(&XB[(size_t)row * 1024 + c4]) =
        *reinterpret_cast<const ushort4*>(o);
    return;
  }
  __shared__ float tl[64][65];
  const float* in; __hip_bfloat16* out; int K, N, Kpad, kb, nb;
  if (b < 1536) {                                    // w1: 16 ktiles x 32 ntiles
    int mat = b / 512, r = b % 512;
    const float* s[3] = {w1a, w1b, w1c};
    in = s[mat]; out = WT1 + (size_t)mat * 2048 * 1024;
    K = 1000; N = 2048; Kpad = 1024; kb = r & 15; nb = r >> 4;
  } else if (b < 3072) {                             // w2: 32 ktiles x 16 ntiles
    int r = b - 1536; int mat = r / 512; r %= 512;
    const float* s[3] = {w2a, w2b, w2c};
    in = s[mat]; out = WT2 + (size_t)mat * 1024 * 2048;
    K = 2048; N = 1024; Kpad = 2048; kb = r & 31; nb = r >> 5;
  } else {                                           // w3: 16 ktiles x 8 ntiles
    int r = b - 3072; int mat = r / 128; r %= 128;
    const float* s[3] = {w3a, w3b, w3c};
    in = s[mat]; out = WT3 + (size_t)mat * 512 * 1024;
    K = 1024; N = 512; Kpad = 1024; kb = r & 15; nb = r >> 4;
  }
  const int kb64 = kb * 64, nb64 = nb * 64;
  const int trow = t >> 4, tc4 = (t & 15) * 4;
#pragma unroll
  for (int it = 0; it < 4; ++it) {
    const int kl = it * 16 + trow;
    const int k = kb64 + kl;
    float4v v = {0.f, 0.f, 0.f, 0.f};
    if (k < K) v = *reinterpret_cast<const float4v*>(&in[(size_t)k * N + nb64 + tc4]);
    tl[kl][tc4 + 0] = v[0]; tl[kl][tc4 + 1] = v[1];
    tl[kl][tc4 + 2] = v[2]; tl[kl][tc4 + 3] = v[3];
  }
  __syncthreads();
  const int ln = t >> 2, ks = (t & 3) * 16;
  short ob[16];
#pragma unroll
  for (int u = 0; u < 16; ++u) {
    __hip_bfloat16 bb = __float2bfloat16(tl[ks + u][ln]);
    ob[u] = *(const short*)&bb;
  }
  __hip_bfloat16* dst = out + (size_t)(nb64 + ln) * Kpad + kb64 + ks;
  *reinterpret_cast<bf16x8*>(dst) = *reinterpret_cast<const bf16x8*>(&ob[0]);
  *reinterpret_cast<bf16x8*>(dst + 8) = *reinterpret_cast<const bf16x8*>(&ob[8]);
}

// ---------------------------------------------------------------------------
// gemm_fast<NJ>: 128 x (NJ*32) tile, BK=32, 4 waves (2m x 2n), RING-3 LDS,
// counted vmcnt (best-measured loop). L = loads/thread/tile: NJ=4 -> 4
// (vmcnt 4), NJ=2 -> 3 (vmcnt 3). launch_bounds(256,3): even 3 blocks/CU.
// Swizzle: 64B rows, slot = colgroup ^ ((row>>1)&3), both sides.
// epi: 1 = bf16+relu (bias by zz), 2 = f32 guarded col<nlimit (bias0),
//      3 = bf16 + relu iff zz<2, 4 = bf16+relu, bias col-select (G1 merged).
// ---------------------------------------------------------------------------
template <int NJ>
__global__ __launch_bounds__(256, 3) void gemm_fast(
    const __hip_bfloat16* __restrict__ A, int lda, size_t Az,
    const __hip_bfloat16* __restrict__ B, int ldb, size_t Bz,
    const float* __restrict__ bias0, const float* __restrict__ bias1,
    const float* __restrict__ bias2,
    void* __restrict__ Cout, int ldc, size_t Cz,
    int nlimit, int NT, int epi, int cm, int cn) {
  __shared__ __hip_bfloat16 smA[3][4096];            // [buf][128 rows x 32]
  __shared__ __hip_bfloat16 smB[3][NJ * 1024];       // [buf][NJ*32 rows x 32]
  const int t = threadIdx.x;
  int zz, mt, nt;
  xcd_map(gridDim.x, gridDim.y, cm, cn, zz, mt, nt);
  const int m0 = mt * 128, n0 = nt * (NJ * 32);
  A += (size_t)zz * Az;
  B += (size_t)zz * Bz;

  const int w = t >> 6, l = t & 63;
  const int wm = (w >> 1) * 64, wn = (w & 1) * (NJ * 16);
  const int fr = l & 15, fq = l >> 4;

  // staging: linear byte L: row=L>>6, slot=(L>>4)&3, colgroup = slot^((row>>1)&3)
  const int r0 = t >> 2;
  const int cg = (t & 3) ^ ((t >> 3) & 3);
  const __hip_bfloat16* gA0 = A + (size_t)(m0 + r0) * lda + cg * 8;
  const __hip_bfloat16* gA1 = gA0 + (size_t)64 * lda;
  const __hip_bfloat16* gB0 = B + (size_t)(n0 + r0) * ldb + cg * 8;
  const __hip_bfloat16* gB1 = gB0 + (size_t)64 * ldb;   // used only if NJ==4

  // ds_read element offsets: row*32 + (fq ^ ((row>>1)&3))*8
  const int soff = (fq ^ ((fr >> 1) & 3)) * 8;
  int offA[4], offB[NJ];
#pragma unroll
  for (int i = 0; i < 4; ++i) offA[i] = (wm + i * 16 + fr) * 32 + soff;
#pragma unroll
  for (int j = 0; j < NJ; ++j) offB[j] = (wn + j * 16 + fr) * 32 + soff;

  f32x4 acc[4][NJ] = {};

#define STG(BUF, KT) do {                                                      \
    const size_t ko_ = (size_t)(KT) * 32;                                      \
    gload16(gA0 + ko_, &smA[BUF][w * 512]);                                    \
    gload16(gA1 + ko_, &smA[BUF][w * 512 + 2048]);                             \
    gload16(gB0 + ko_, &smB[BUF][w * 512]);                                    \
    if (NJ == 4) gload16(gB1 + ko_, &smB[BUF][w * 512 + 2048]);                \
  } while (0)

  // prologue: stage tiles 0,1 into bufs 0,1 (2L loads/thread outstanding)
  STG(0, 0);
  STG(1, 1);

  int cur = 0;
  for (int T = 0; T < NT; ++T) {
    // wait: tile-T stages done, tile-T+1's L still in flight
    if (T == NT - 1)
      asm volatile("s_waitcnt vmcnt(0)" ::: "memory");
    else if (NJ == 4)
      asm volatile("s_waitcnt vmcnt(4)" ::: "memory");
    else
      asm volatile("s_waitcnt vmcnt(3)" ::: "memory");
    __builtin_amdgcn_s_barrier();                    // all waves' T-stages done
    __builtin_amdgcn_sched_barrier(0);
    bf16x8 af[4], bf[NJ];
#pragma unroll
    for (int i = 0; i < 4; ++i)
      af[i] = *reinterpret_cast<const bf16x8*>(&smA[cur][offA[i]]);
#pragma unroll
    for (int j = 0; j < NJ; ++j)
      bf[j] = *reinterpret_cast<const bf16x8*>(&smB[cur][offB[j]]);
    if (T + 2 < NT) {
      const int nb_ = (cur + 2 >= 3) ? cur - 1 : cur + 2;
      STG(nb_, T + 2);
    }
#pragma unroll
    for (int i = 0; i < 4; ++i)
#pragma unroll
      for (int j = 0; j < NJ; ++j)
        acc[i][j] = __builtin_amdgcn_mfma_f32_16x16x32_bf16(af[i], bf[j], acc[i][j], 0, 0, 0);
    cur = (cur + 1 >= 3) ? 0 : cur + 1;
  }
#undef STG

  // epilogue
  const float* bz = (zz == 0) ? bias0 : ((zz == 1) ? bias1 : bias2);
  const bool dorelu = (epi == 1) || (epi == 4) || (epi == 3 && zz < 2);
  float bv[NJ];
#pragma unroll
  for (int j = 0; j < NJ; ++j) {
    const int col = n0 + wn + j * 16 + fr;
    if (epi == 4) {
      const float* bsel = (col < 2048) ? bias0 : ((col < 4096) ? bias1 : bias2);
      bv[j] = bsel[col & 2047];
    } else if (epi == 2) {
      bv[j] = (col < nlimit) ? bias0[col] : 0.f;
    } else {
      bv[j] = bz[col];
    }
  }
#pragma unroll
  for (int i = 0; i < 4; ++i) {
#pragma unroll
    for (int j = 0; j < NJ; ++j) {
      const int col = n0 + wn + j * 16 + fr;
#pragma unroll
      for (int rr = 0; rr < 4; ++rr) {
        const int row = m0 + wm + i * 16 + fq * 4 + rr;
        float v = acc[i][j][rr] + bv[j];
        if (dorelu) v = fmaxf(v, 0.f);
        if (epi == 2) {
          if (col < nlimit)
            ((float*)Cout)[(size_t)row * ldc + col] = v;
        } else {
          ((__hip_bfloat16*)Cout + (size_t)zz * Cz)[(size_t)row * ldc + col] =
              __float2bfloat16(v);
        }
      }
    }
  }
}

// ---- per-head partial M = kh^T vh (64x64) and ksum, over 128-row chunks ---
__global__ __launch_bounds__(256) void kv_outer(const __hip_bfloat16* __restrict__ QKV, int ld,
                                                float* __restrict__ part) {
  __shared__ __hip_bfloat16 kt[128][64];
  __shared__ __hip_bfloat16 vt[128][64];
  const int t = threadIdx.x;
  const int n0 = blockIdx.x * 128;
  const int h = blockIdx.y;
#pragma unroll
  for (int it = 0; it < 4; ++it) {
    int r = it * 32 + (t >> 3);
    int c = (t & 7) * 8;
    const __hip_bfloat16* kr = &QKV[(size_t)(n0 + r) * ld + 512 + h * 64 + c];
    const __hip_bfloat16* vr = &QKV[(size_t)(n0 + r) * ld + 1024 + h * 64 + c];
    *reinterpret_cast<bf16x8*>(&kt[r][c]) = *reinterpret_cast<const bf16x8*>(kr);
    *reinterpret_cast<bf16x8*>(&vt[r][c]) = *reinterpret_cast<const bf16x8*>(vr);
  }
  __syncthreads();
  const int i = t >> 2, j0 = (t & 3) << 4;
  float acc[16] = {};
  float ks = 0.f;
  for (int r = 0; r < 128; ++r) {
    float kv = __bfloat162float(kt[r][i]);
    ks += kv;
    bf16x8 va = *reinterpret_cast<const bf16x8*>(&vt[r][j0]);
    bf16x8 vb = *reinterpret_cast<const bf16x8*>(&vt[r][j0 + 8]);
#pragma unroll
    for (int jj = 0; jj < 8; ++jj) {
      ushort ua = (ushort)((const short*)&va)[jj];
      ushort ub = (ushort)((const short*)&vb)[jj];
      acc[jj]     += kv * __bfloat162float(*(const __hip_bfloat16*)&ua);
      acc[8 + jj] += kv * __bfloat162float(*(const __hip_bfloat16*)&ub);
    }
  }
  float* dst = part + ((size_t)blockIdx.x * 8 + h) * 4160;
#pragma unroll
  for (int jj = 0; jj < 16; ++jj) dst[i * 64 + j0 + jj] = acc[jj];
  if ((t & 3) == 0) dst[4096 + i] = ks;
}

// ---- reduce 32 partials -> Mfin [8][4160]; 130 blocks x 256 threads -------
__global__ __launch_bounds__(256) void reduce_m(const float* __restrict__ part,
                                                float* __restrict__ Mfin) {
  const int g = blockIdx.x * 256 + threadIdx.x;      // 33280 = 8*4160 exactly
  if (g >= 8 * 4160) return;
  const int h = g / 4160, idx = g % 4160;
  float s = 0.f;
#pragma unroll 4
  for (int c = 0; c < 32; ++c) s += part[((size_t)c * 8 + h) * 4160 + idx];
  Mfin[(size_t)h * 4160 + idx] = s;
}

// ---- fused: blocks [0,32): MW^T = M_h @ Wo_h (bf16); [32,1056): q̃ --------
__global__ __launch_bounds__(256) void mwq(const float* __restrict__ Mfin,
                                           const float* __restrict__ wo,
                                           __hip_bfloat16* __restrict__ MWT,
                                           const __hip_bfloat16* __restrict__ QKV,
                                           __hip_bfloat16* __restrict__ QT) {
  const int t = threadIdx.x;
  if (blockIdx.x < 32) {
    __shared__ float Ml[64][64];
    const int h = blockIdx.x >> 2;
    const int j = (blockIdx.x & 3) * 256 + t;
    const float* M = Mfin + (size_t)h * 4160;
    for (int e = t; e < 4096; e += 256)
      Ml[e >> 6][e & 63] = M[e];
    __syncthreads();
    float wcol[64];
    const bool valid = (j < 1000);
#pragma unroll
    for (int d = 0; d < 64; ++d)
      wcol[d] = valid ? wo[(size_t)(h * 64 + d) * 1000 + j] : 0.f;
    short ob[64];
#pragma unroll
    for (int i = 0; i < 64; ++i) {
      float a = 0.f;
#pragma unroll
      for (int d = 0; d < 64; ++d) a += Ml[i][d] * wcol[d];
      __hip_bfloat16 bb = __float2bfloat16(a);
      ob[i] = *(const short*)&bb;
    }
    __hip_bfloat16* dst = MWT + (size_t)j * 512 + h * 64;
#pragma unroll
    for (int v = 0; v < 8; ++v)
      *reinterpret_cast<bf16x8*>(dst + v * 8) = *reinterpret_cast<const bf16x8*>(&ob[v * 8]);
  } else {
    const int bid = blockIdx.x - 32;
    const int r = bid * 4 + (t >> 6);
    const int c = (t & 63) * 8;
    const int h = (t & 63) >> 3;
    bf16x8 qv = *reinterpret_cast<const bf16x8*>(&QKV[(size_t)r * 1536 + c]);
    float qf[8];
#pragma unroll
    for (int j = 0; j < 8; ++j) {
      ushort u = (ushort)((const short*)&qv)[j];
      qf[j] = __bfloat162float(*(const __hip_bfloat16*)&u);
    }
    const float* ks = Mfin + (size_t)h * 4160 + 4096 + (c & 63);
    float s = 0.f;
#pragma unroll
    for (int j = 0; j < 8; ++j) s += qf[j] * ks[j];
    s += __shfl_xor(s, 1, 8);
    s += __shfl_xor(s, 2, 8);
    s += __shfl_xor(s, 4, 8);
    const float inv = 0.125f / (s * 0.125f + 1e-8f);
    bf16x8 o;
#pragma unroll
    for (int j = 0; j < 8; ++j) {
      __hip_bfloat16 bb = __float2bfloat16(qf[j] * inv);
      ((short*)&o)[j] = *(const short*)&bb;
    }
    *reinterpret_cast<bf16x8*>(&QT[(size_t)r * 512 + c]) = o;
  }
}

// ---------------------------------------------------------------------------
extern "C" void kernel_launch(void* const* d_in, const int* in_sizes, int n_in,
                              void* d_out, int out_size, void* d_ws, size_t ws_size,
                              hipStream_t stream) {
  const float* batch = (const float*)d_in[0];
  const float* w1[3] = {(const float*)d_in[1],  (const float*)d_in[7],  (const float*)d_in[13]};
  const float* b1[3] = {(const float*)d_in[2],  (const float*)d_in[8],  (const float*)d_in[14]};
  const float* w2[3] = {(const float*)d_in[3],  (const float*)d_in[9],  (const float*)d_in[15]};
  const float* b2[3] = {(const float*)d_in[4],  (const float*)d_in[10], (const float*)d_in[16]};
  const float* w3[3] = {(const float*)d_in[5],  (const float*)d_in[11], (const float*)d_in[17]};
  const float* b3[3] = {(const float*)d_in[6],  (const float*)d_in[12], (const float*)d_in[18]};
  const float* wow   = (const float*)d_in[19];
  const float* wob   = (const float*)d_in[20];

  char* ws = (char*)d_ws;
  __hip_bfloat16* XB  = (__hip_bfloat16*)(ws + OFF_XB);
  __hip_bfloat16* WT1 = (__hip_bfloat16*)(ws + OFF_WT1);
  __hip_bfloat16* WT2 = (__hip_bfloat16*)(ws + OFF_WT2);
  __hip_bfloat16* WT3 = (__hip_bfloat16*)(ws + OFF_WT3);
  __hip_bfloat16* MWT = (__hip_bfloat16*)(ws + OFF_MWT);
  __hip_bfloat16* H1  = (__hip_bfloat16*)(ws + OFF_H1);
  __hip_bfloat16* H2  = (__hip_bfloat16*)(ws + OFF_H2);
  __hip_bfloat16* QKV = (__hip_bfloat16*)(ws + OFF_QKV);
  float*          MP  = (float*)(ws + OFF_MP);
  float*          MF  = (float*)(ws + OFF_MF);
  __hip_bfloat16* QT  = (__hip_bfloat16*)(ws + OFF_QT);
  float*          OUT = (float*)d_out;

  // 1) mega-prep: all weight transposes + batch pad/convert (1 launch)
  prep<<<7552, 256, 0, stream>>>(w1[0], w1[1], w1[2], w2[0], w2[1], w2[2],
                                 w3[0], w3[1], w3[2], batch, WT1, WT2, WT3, XB);

  // 2) MLPs (gemm_fast 128-row tiles, ring-3, even 3 blocks/CU)
  // G1 (merged q|k|v): [4096,1024]@[1024,6144] -> H1. 1536 blocks = 2 even rounds.
  gemm_fast<4><<<dim3(48, 32, 1), 256, 0, stream>>>(
      XB, 1024, 0, WT1, 1024, 0, b1[0], b1[1], b1[2], H1, 6144, 0,
      6144, 32, 4, 16, 12);
  // G2 z-batched: [4096,2048]@[2048,1024] -> H2 (relu). 768 blocks = 3/CU even.
  gemm_fast<4><<<dim3(8, 32, 3), 256, 0, stream>>>(
      H1, 6144, 2048, WT2, 2048, (size_t)1024 * 2048,
      b2[0], b2[1], b2[2], H2, 3072, 1024, 1024, 64, 1, 8, 4);
  // G3 z-batched: [4096,1024]@[1024,512] -> QKV. 128x64 tiles, 768 blocks even.
  gemm_fast<2><<<dim3(8, 32, 3), 256, 0, stream>>>(
      H2, 3072, 1024, WT3, 1024, (size_t)512 * 1024,
      b3[0], b3[1], b3[2], QKV, 1536, 512, 512, 32, 3, 8, 4);

  // 3) attention reductions + fusion into out-proj operands
  kv_outer<<<dim3(32, 8), 256, 0, stream>>>(QKV, 1536, MP);
  reduce_m<<<130, 256, 0, stream>>>(MP, MF);
  mwq<<<1056, 256, 0, stream>>>(MF, wow, MWT, QKV, QT);

  // 4) fused attention+output projection: q̃ @ MW^T -> d_out fp32.
  // 128x64 tiles -> 512 blocks = 2/CU even.
  gemm_fast<2><<<dim3(16, 32, 1), 256, 0, stream>>>(
      QT, 512, 0, MWT, 512, 0, wob, wob, wob, OUT, 1000, 0,
      1000, 16, 2, 16, 4);

  (void)in_sizes; (void)n_in; (void)out_size; (void)ws_size;
}